// Round 15
// baseline (504.164 us; speedup 1.0000x reference)
//
#include <hip/hip_runtime.h>
#include <hip/hip_bf16.h>

#define NR 512
#define DF 576
#define LOG2E 1.4426950408889634f

#if __has_builtin(__builtin_amdgcn_exp2f)
#define EXP2F __builtin_amdgcn_exp2f
#else
#define EXP2F exp2f
#endif

typedef _Float16 f16x8 __attribute__((ext_vector_type(8)));
typedef float f32x4 __attribute__((ext_vector_type(4)));
typedef unsigned short u16x8 __attribute__((ext_vector_type(8)));

// Workspace layout (bytes):
//  PT[kc(3)][w(3)][512][576] fp32 : 10,616,832
//  XF fp16 frag plane             : 589,824   @ 10,616,832
//  WF fp16 frag plane (3 w)       : 1,990,656 @ 11,206,656
//  BAR (2 counters + pad)         : 128       @ 13,197,312
#define PT_OFF  0
#define XF_OFF  10616832
#define WF_OFF  11206656
#define BAR_OFF 13197312
#define WF_PER_W 331776

#define M_NODES 32
#define CHUNKS  16
#define JPC     36
#define CSTRIDE 19

// ---------------------------------------------------------------------------
// Phase 1: fp32 -> fp16 planes in MFMA frag order.  161280 tasks.
// ---------------------------------------------------------------------------
static __device__ __forceinline__ void phase_prep(
    int t, const float* __restrict__ X,
    const float* __restrict__ Wq, const float* __restrict__ Wk,
    const float* __restrict__ Wv,
    unsigned short* __restrict__ XF, unsigned short* __restrict__ WF)
{
    if (t >= 161280) return;
    const float* src; unsigned short* d; int flat;
    if (t < 36864) { src = X; d = XF; flat = t * 8; }
    else {
        const int tw = t - 36864;
        const int w  = tw / 41472;
        const int r  = tw - w * 41472;
        src = (w == 0) ? Wq : (w == 1) ? Wk : Wv;
        d = WF + (size_t)w * WF_PER_W;
        flat = r * 8;
    }
    const int row  = flat / DF;
    const int k    = flat - row * DF;
    const int off  = (((row >> 4) * 18 + (k >> 5)) * 64
                      + (row & 15) + 16 * ((k & 31) >> 3)) * 8;

    const float4 v0 = *reinterpret_cast<const float4*>(src + (size_t)row * DF + k);
    const float4 v1 = *reinterpret_cast<const float4*>(src + (size_t)row * DF + k + 4);
    float fv[8] = {v0.x, v0.y, v0.z, v0.w, v1.x, v1.y, v1.z, v1.w};
    u16x8 h;
#pragma unroll
    for (int e = 0; e < 8; ++e)
        h[e] = __builtin_bit_cast(unsigned short, (_Float16)fv[e]);
    *reinterpret_cast<u16x8*>(d + off) = h;
}

// ---------------------------------------------------------------------------
// Phase 2: fp16 split-K(3) GEMM, LDS-free.  2592 wave-jobs, 32x32 tile.
// Staged in 2 half-chunks (12 b128 loads then 12 MFMA) to stay <=128 VGPR.
// ---------------------------------------------------------------------------
static __device__ __forceinline__ void phase_gemm(
    int job, int lane,
    const unsigned short* __restrict__ XF, const unsigned short* __restrict__ WF,
    float* __restrict__ PT)
{
    if (job >= 2592) return;
    const int w  = job / 864;
    int r = job - w * 864;
    const int kc = r / 288;  r -= kc * 288;
    const int rowt = r / 18;
    const int colt = r - rowt * 18;

    const unsigned short* wf = WF + (size_t)w * WF_PER_W;

    const int kbase = kc * 6 * 512;
    const int a0 = (rowt * 2    ) * 9216 + kbase + lane * 8;
    const int a1 = (rowt * 2 + 1) * 9216 + kbase + lane * 8;
    const int b0 = (colt * 2    ) * 9216 + kbase + lane * 8;
    const int b1 = (colt * 2 + 1) * 9216 + kbase + lane * 8;

    f32x4 acc[2][2] = {{{0.f,0.f,0.f,0.f},{0.f,0.f,0.f,0.f}},
                       {{0.f,0.f,0.f,0.f},{0.f,0.f,0.f,0.f}}};

#pragma unroll
    for (int half = 0; half < 2; ++half) {
        f16x8 fa0[3], fa1[3], fb0[3], fb1[3];
#pragma unroll
        for (int s = 0; s < 3; ++s) {
            const int o = (half * 3 + s) * 512;
            fa0[s] = *reinterpret_cast<const f16x8*>(XF + a0 + o);
            fa1[s] = *reinterpret_cast<const f16x8*>(XF + a1 + o);
            fb0[s] = *reinterpret_cast<const f16x8*>(wf + b0 + o);
            fb1[s] = *reinterpret_cast<const f16x8*>(wf + b1 + o);
        }
#pragma unroll
        for (int s = 0; s < 3; ++s) {
            acc[0][0] = __builtin_amdgcn_mfma_f32_16x16x32_f16(fa0[s], fb0[s], acc[0][0], 0, 0, 0);
            acc[0][1] = __builtin_amdgcn_mfma_f32_16x16x32_f16(fa0[s], fb1[s], acc[0][1], 0, 0, 0);
            acc[1][0] = __builtin_amdgcn_mfma_f32_16x16x32_f16(fa1[s], fb0[s], acc[1][0], 0, 0, 0);
            acc[1][1] = __builtin_amdgcn_mfma_f32_16x16x32_f16(fa1[s], fb1[s], acc[1][1], 0, 0, 0);
        }
    }

    float* P = PT + (size_t)(kc * 3 + w) * NR * DF;
#pragma unroll
    for (int ni = 0; ni < 2; ++ni) {
        const int col = colt * 32 + ni * 16 + (lane & 15);
#pragma unroll
        for (int mi = 0; mi < 2; ++mi) {
            const int row0 = rowt * 32 + mi * 16 + (lane >> 4) * 4;
#pragma unroll
            for (int rr = 0; rr < 4; ++rr)
                P[(size_t)(row0 + rr) * DF + col] = acc[mi][ni][rr];
        }
    }
}

// ---------------------------------------------------------------------------
// Phase 3: rank-1 attention (tilted-mean interp, 32 nodes), fused split-K
// reduce (+bias).  512 threads; t<64 also handle columns 512+t.
// (Validated in R10 at absmax 4.88e-4.)
// ---------------------------------------------------------------------------
static __device__ __forceinline__ void phase_attn(
    int n, int t, const float* __restrict__ PT,
    const float* __restrict__ bq, const float* __restrict__ bk,
    const float* __restrict__ bv, float* __restrict__ out)
{
    __shared__ __align__(16) float4 KV4[CHUNKS * CSTRIDE];
    __shared__ __align__(16) float Pf[DF];
    __shared__ __align__(16) float Pg[DF];
    __shared__ float Rt[M_NODES];
    __shared__ float range[2];

    const size_t pl = (size_t)NR * DF;
    float qq0, qq1 = 0.f;
    {
        const size_t nb = (size_t)n * DF + t;
        qq0 = ((PT[nb] + PT[pl * 3 + nb]) + PT[pl * 6 + nb]) + bq[t];
        const float kv = ((PT[pl + nb] + PT[pl * 4 + nb]) + PT[pl * 7 + nb]) + bk[t];
        const float vv = ((PT[pl * 2 + nb] + PT[pl * 5 + nb]) + PT[pl * 8 + nb]) + bv[t];
        const int c = t / JPC, jl = t - (t / JPC) * JPC;
        float2* dst = reinterpret_cast<float2*>(&KV4[c * CSTRIDE + (jl >> 1)]);
        dst[jl & 1] = make_float2(kv * LOG2E, vv);
        Pf[t] = qq0;
    }
    if (t < 64) {
        const int j = 512 + t;
        const size_t nb = (size_t)n * DF + j;
        qq1 = ((PT[nb] + PT[pl * 3 + nb]) + PT[pl * 6 + nb]) + bq[j];
        const float kv = ((PT[pl + nb] + PT[pl * 4 + nb]) + PT[pl * 7 + nb]) + bk[j];
        const float vv = ((PT[pl * 2 + nb] + PT[pl * 5 + nb]) + PT[pl * 8 + nb]) + bv[j];
        const int c = j / JPC, jl = j - (j / JPC) * JPC;
        float2* dst = reinterpret_cast<float2*>(&KV4[c * CSTRIDE + (jl >> 1)]);
        dst[jl & 1] = make_float2(kv * LOG2E, vv);
        Pf[j] = qq1;
    }
    __syncthreads();

    if (t < 64) {
        float lo = Pf[t], hi = lo;
#pragma unroll
        for (int r = 1; r < 9; ++r) {
            float v = Pf[t + 64 * r];
            lo = fminf(lo, v); hi = fmaxf(hi, v);
        }
#pragma unroll
        for (int s = 32; s; s >>= 1) {
            lo = fminf(lo, __shfl_xor(lo, s, 64));
            hi = fmaxf(hi, __shfl_xor(hi, s, 64));
        }
        if (t == 0) { range[0] = lo; range[1] = hi; }
    }
    __syncthreads();

    const float qmin = range[0], qmax = range[1];
    const float h    = fmaxf((qmax - qmin) * (1.0f / (M_NODES - 5)), 1e-6f);
    const float qlo  = qmin - 2.0f * h;

    const int m = t >> 4;
    const int c = t & 15;
    const float qm = qlo + h * (float)m;
    const float4* kvp = KV4 + c * CSTRIDE;
    float f0 = 0.f, f1 = 0.f, g0 = 0.f, g1 = 0.f;
#pragma unroll
    for (int jj = 0; jj < JPC / 2; ++jj) {
        float4 p = kvp[jj];
        float e0 = EXP2F(qm * p.x);
        float e1 = EXP2F(qm * p.z);
        g0 += e0; g1 += e1;
        f0 = fmaf(e0, p.y, f0);
        f1 = fmaf(e1, p.w, f1);
    }
    __syncthreads();
    Pf[t] = f0 + f1;
    Pg[t] = g0 + g1;
    __syncthreads();

    if (t < M_NODES) {
        const float4* pf4 = reinterpret_cast<const float4*>(Pf) + t * 4;
        const float4* pg4 = reinterpret_cast<const float4*>(Pg) + t * 4;
        float fs = 0.f, gs = 0.f;
#pragma unroll
        for (int i = 0; i < 4; ++i) {
            float4 a = pf4[i], b = pg4[i];
            fs += (a.x + a.y) + (a.z + a.w);
            gs += (b.x + b.y) + (b.z + b.w);
        }
        Rt[t] = fs / gs;
    }
    __syncthreads();

    float qv[2]; int cols[2];
    qv[0] = qq0; cols[0] = t;
    qv[1] = qq1; cols[1] = 512 + t;
    const int ncol = (t < 64) ? 2 : 1;
    for (int ii = 0; ii < ncol; ++ii) {
        const float u = (qv[ii] - qlo) * (1.0f / h);
        int i0 = (int)u;
        i0 = (i0 < 1) ? 1 : (i0 > M_NODES - 3 ? M_NODES - 3 : i0);
        const float tf = u - (float)i0;
        const float a  = Rt[i0 - 1];
        const float b  = Rt[i0];
        const float cc = Rt[i0 + 1];
        const float d  = Rt[i0 + 2];
        const float m0 = 0.5f * (cc - a);
        const float m1 = 0.5f * (d - b);
        const float dd = cc - b;
        out[(size_t)n * DF + cols[ii]] =
            b + tf * (m0 + tf * ((3.f * dd - 2.f * m0 - m1)
                                 + tf * (m0 + m1 - 2.f * dd)));
    }
}

// ---------------------------------------------------------------------------
// Custom lightweight grid barrier (counters zeroed by hipMemsetAsync each
// launch).  All 512 blocks are co-resident: 512 thr @ <=128 VGPR -> 2
// blocks/CU x 256 CU = 512.  Arrive: release-fence + 1 atomicAdd per block;
// wait: thread-0 s_sleep poll; then acquire-fence.
// ---------------------------------------------------------------------------
static __device__ __forceinline__ void grid_bar(unsigned int* cnt, unsigned target)
{
    __threadfence();                 // release: make phase writes visible
    __syncthreads();
    if (threadIdx.x == 0) {
        __hip_atomic_fetch_add(cnt, 1u, __ATOMIC_RELEASE, __HIP_MEMORY_SCOPE_AGENT);
        while (__hip_atomic_load(cnt, __ATOMIC_ACQUIRE, __HIP_MEMORY_SCOPE_AGENT) < target)
            __builtin_amdgcn_s_sleep(4);
    }
    __syncthreads();
    __threadfence();                 // acquire: invalidate stale cache lines
}

__global__ __launch_bounds__(512, 4) void mega2_kernel(
    const float* X, const float* Wq, const float* Wk, const float* Wv,
    const float* bq, const float* bk, const float* bv,
    unsigned short* XF, unsigned short* WF,
    float* PT, unsigned int* bar, float* out)
{
    const int tid = threadIdx.x;
    const int bid = blockIdx.x;

    phase_prep(bid * 512 + tid, X, Wq, Wk, Wv, XF, WF);
    grid_bar(bar + 0, gridDim.x);

    phase_gemm(bid * 8 + (tid >> 6), tid & 63, XF, WF, PT);
    grid_bar(bar + 16, gridDim.x);   // separate cache line

    phase_attn(bid, tid, PT, bq, bk, bv, out);
}

// ---------------------------------------------------------------------------
extern "C" void kernel_launch(void* const* d_in, const int* in_sizes, int n_in,
                              void* d_out, int out_size, void* d_ws, size_t ws_size,
                              hipStream_t stream) {
    const float* x  = (const float*)d_in[0];
    const float* Wq = (const float*)d_in[1];
    const float* bq = (const float*)d_in[2];
    const float* Wk = (const float*)d_in[3];
    const float* bk = (const float*)d_in[4];
    const float* Wv = (const float*)d_in[5];
    const float* bv = (const float*)d_in[6];

    char* ws = (char*)d_ws;
    float*          PT  = (float*)(ws + PT_OFF);
    unsigned short* XF  = (unsigned short*)(ws + XF_OFF);
    unsigned short* WF  = (unsigned short*)(ws + WF_OFF);
    unsigned int*   bar = (unsigned int*)(ws + BAR_OFF);

    // zero the two barrier counters (graph-capturable, replay-deterministic)
    hipMemsetAsync(bar, 0, 128, stream);

    mega2_kernel<<<512, 512, 0, stream>>>(
        x, Wq, Wk, Wv, bq, bk, bv, XF, WF, PT, bar, (float*)d_out);
}

// Round 16
// 19.292 us; speedup vs baseline: 26.1332x; 26.1332x over previous
//
#include <hip/hip_runtime.h>
#include <hip/hip_bf16.h>

#define NR 512
#define DF 576
#define LOG2E 1.4426950408889634f

#if __has_builtin(__builtin_amdgcn_exp2f)
#define EXP2F __builtin_amdgcn_exp2f
#else
#define EXP2F exp2f
#endif

typedef _Float16 f16x8 __attribute__((ext_vector_type(8)));
typedef float f32x4 __attribute__((ext_vector_type(4)));

// Workspace layout (bytes):
//  PTQ fp32 [kc(3)][512][576]  : 3,538,944  @ 0
//  PTK fp16 [kc(3)][512][576]  : 1,769,472  @ 3,538,944   (pre-scaled LOG2E)
//  PTV fp16 [kc(3)][512][576]  : 1,769,472  @ 5,308,416
#define PTQ_OFF 0
#define PTK_OFF 3538944
#define PTV_OFF 5308416

// ---------------------------------------------------------------------------
// Kernel 1: QKV GEMM with in-kernel fp32->fp16 conversion via LDS.
// Grid (9,8,9): x=colt2(64 cols), y=rowt2(64 rows), z=w*3+kc (K-chunk 192).
// 256 thr = 4 waves (2x2).  Per block:
//   phase A: load X[64x192] + W[64x192] fp32 row-major (coalesced: 24 thr
//     cover one 768B row), convert to fp16, write frag-ordered LDS
//     [fr(4)][ks(6)][slot(64)][8] with slot = lane' ^ ks (bank-spread;
//     reads stay conflict-free since lane^ks is a permutation).
//   phase B: per wave 24 ds_read_b128 + 24 MFMA (4 indep chains), as R11.
// Epilogue: w==0 -> PTQ fp32; w==1 -> PTK fp16 (acc*LOG2E); w==2 -> PTV fp16.
// Total fp32 read traffic = 63.7 MB (same bytes as the old fp16-plane path),
// but the separate prep dispatch + its boundary flush are gone.
// ---------------------------------------------------------------------------
__global__ __launch_bounds__(256) void qkv_lds_kernel(
    const float* __restrict__ X,
    const float* __restrict__ Wq, const float* __restrict__ Wk,
    const float* __restrict__ Wv,
    float* __restrict__ PTQ, _Float16* __restrict__ PTK,
    _Float16* __restrict__ PTV)
{
    const int w  = blockIdx.z / 3;
    const int kc = blockIdx.z - w * 3;
    const float* W = (w == 0) ? Wq : (w == 1) ? Wk : Wv;

    const int tid  = threadIdx.x;
    const int lane = tid & 63;
    const int wv   = tid >> 6;
    const int rt   = wv >> 1;            // wave row-tile 0..1
    const int ct   = wv & 1;             // wave col-tile 0..1
    const int brow0 = blockIdx.y * 64;
    const int bcol0 = blockIdx.x * 64;
    const int kbase = kc * 192;

    __shared__ _Float16 LA[4 * 6 * 64 * 8];   // 24 KB
    __shared__ _Float16 LB[4 * 6 * 64 * 8];   // 24 KB

    // ---- phase A: convert panels into frag-ordered LDS ----
#pragma unroll
    for (int it = 0; it < 6; ++it) {
        const int task = it * 256 + tid;       // 0..1535
        const int r  = task / 24;              // local row 0..63
        const int kq = task - r * 24;          // k-octet 0..23
        const int k  = kq * 8;

        const int fr   = r >> 4;
        const int ks   = k >> 5;
        const int lp   = (r & 15) + 16 * ((k & 31) >> 3);
        const int slot = lp ^ ks;
        _Float16* da = &LA[((fr * 6 + ks) * 64 + slot) * 8];
        _Float16* db = &LB[((fr * 6 + ks) * 64 + slot) * 8];

        {
            const float* s = X + (size_t)(brow0 + r) * DF + kbase + k;
            const float4 v0 = *reinterpret_cast<const float4*>(s);
            const float4 v1 = *reinterpret_cast<const float4*>(s + 4);
            f16x8 h = {(_Float16)v0.x, (_Float16)v0.y, (_Float16)v0.z, (_Float16)v0.w,
                       (_Float16)v1.x, (_Float16)v1.y, (_Float16)v1.z, (_Float16)v1.w};
            *reinterpret_cast<f16x8*>(da) = h;
        }
        {
            const float* s = W + (size_t)(bcol0 + r) * DF + kbase + k;
            const float4 v0 = *reinterpret_cast<const float4*>(s);
            const float4 v1 = *reinterpret_cast<const float4*>(s + 4);
            f16x8 h = {(_Float16)v0.x, (_Float16)v0.y, (_Float16)v0.z, (_Float16)v0.w,
                       (_Float16)v1.x, (_Float16)v1.y, (_Float16)v1.z, (_Float16)v1.w};
            *reinterpret_cast<f16x8*>(db) = h;
        }
    }
    __syncthreads();

    // ---- phase B: MFMA from LDS ----
    f32x4 acc[2][2] = {{{0.f,0.f,0.f,0.f},{0.f,0.f,0.f,0.f}},
                       {{0.f,0.f,0.f,0.f},{0.f,0.f,0.f,0.f}}};
#pragma unroll
    for (int half = 0; half < 2; ++half) {
        f16x8 fa[2][3], fb[2][3];
#pragma unroll
        for (int s = 0; s < 3; ++s) {
            const int ks = half * 3 + s;
            const int sl = (lane ^ ks) * 8;
#pragma unroll
            for (int mi = 0; mi < 2; ++mi)
                fa[mi][s] = *reinterpret_cast<const f16x8*>(
                    &LA[((rt * 2 + mi) * 6 + ks) * 512 + sl]);
#pragma unroll
            for (int ni = 0; ni < 2; ++ni)
                fb[ni][s] = *reinterpret_cast<const f16x8*>(
                    &LB[((ct * 2 + ni) * 6 + ks) * 512 + sl]);
        }
#pragma unroll
        for (int s = 0; s < 3; ++s) {
            acc[0][0] = __builtin_amdgcn_mfma_f32_16x16x32_f16(fa[0][s], fb[0][s], acc[0][0], 0, 0, 0);
            acc[0][1] = __builtin_amdgcn_mfma_f32_16x16x32_f16(fa[0][s], fb[1][s], acc[0][1], 0, 0, 0);
            acc[1][0] = __builtin_amdgcn_mfma_f32_16x16x32_f16(fa[1][s], fb[0][s], acc[1][0], 0, 0, 0);
            acc[1][1] = __builtin_amdgcn_mfma_f32_16x16x32_f16(fa[1][s], fb[1][s], acc[1][1], 0, 0, 0);
        }
    }

    // ---- epilogue ----
    const size_t pl = (size_t)NR * DF;
#pragma unroll
    for (int ni = 0; ni < 2; ++ni) {
        const int col = bcol0 + ct * 32 + ni * 16 + (lane & 15);
#pragma unroll
        for (int mi = 0; mi < 2; ++mi) {
            const int row0 = brow0 + rt * 32 + mi * 16 + (lane >> 4) * 4;
#pragma unroll
            for (int r = 0; r < 4; ++r) {
                const size_t idx = kc * pl + (size_t)(row0 + r) * DF + col;
                const float v = acc[mi][ni][r];
                if (w == 0)      PTQ[idx] = v;
                else if (w == 1) PTK[idx] = (_Float16)(v * LOG2E);
                else             PTV[idx] = (_Float16)v;
            }
        }
    }
}

// ---------------------------------------------------------------------------
// Kernel 2: rank-1 attention via tilted-mean interpolation (36 nodes x 16
// chunks, validated structure), fused 3-way split-K reduce (+bias).
// K partials arrive pre-scaled by LOG2E (fold bias as bk*LOG2E).
// ---------------------------------------------------------------------------
#define M_NODES 36
#define CHUNKS  16
#define JPC     36
#define CSTRIDE 19

__global__ __launch_bounds__(576) void attn_interp_kernel(
    const float* __restrict__ PTQ, const _Float16* __restrict__ PTK,
    const _Float16* __restrict__ PTV,
    const float* __restrict__ bq, const float* __restrict__ bk,
    const float* __restrict__ bv,
    float* __restrict__ out)
{
    const int n = blockIdx.x;
    const int t = threadIdx.x;
    const size_t nb = (size_t)n * DF + t;
    const size_t pl = (size_t)NR * DF;

    const float qv = ((PTQ[nb] + PTQ[pl + nb]) + PTQ[pl * 2 + nb]) + bq[t];
    const float kl = ((float)PTK[nb] + (float)PTK[pl + nb] + (float)PTK[pl * 2 + nb])
                     + bk[t] * LOG2E;
    const float vv = ((float)PTV[nb] + (float)PTV[pl + nb] + (float)PTV[pl * 2 + nb])
                     + bv[t];

    __shared__ __align__(16) float4 KV4[CHUNKS * CSTRIDE];
    __shared__ __align__(16) float Pf[DF];
    __shared__ __align__(16) float Pg[DF];
    __shared__ float Rt[M_NODES];
    __shared__ float range[2];

    {
        const int c  = t / JPC;
        const int jl = t - c * JPC;
        float2* dst = reinterpret_cast<float2*>(&KV4[c * CSTRIDE + (jl >> 1)]);
        dst[jl & 1] = make_float2(kl, vv);
    }
    Pf[t] = qv;
    __syncthreads();

    if (t < 64) {
        float lo = Pf[t], hi = lo;
#pragma unroll
        for (int r = 1; r < 9; ++r) {
            float v = Pf[t + 64 * r];
            lo = fminf(lo, v); hi = fmaxf(hi, v);
        }
#pragma unroll
        for (int s = 32; s; s >>= 1) {
            lo = fminf(lo, __shfl_xor(lo, s, 64));
            hi = fmaxf(hi, __shfl_xor(hi, s, 64));
        }
        if (t == 0) { range[0] = lo; range[1] = hi; }
    }
    __syncthreads();

    const float qmin = range[0], qmax = range[1];
    const float h    = fmaxf((qmax - qmin) * (1.0f / (M_NODES - 5)), 1e-6f);
    const float qlo  = qmin - 2.0f * h;

    const int m = t >> 4;
    const int c = t & 15;
    const float qm = qlo + h * (float)m;
    const float4* kvp = KV4 + c * CSTRIDE;
    float f0 = 0.f, f1 = 0.f, g0 = 0.f, g1 = 0.f;
#pragma unroll
    for (int jj = 0; jj < JPC / 2; ++jj) {
        float4 p = kvp[jj];
        float e0 = EXP2F(qm * p.x);
        float e1 = EXP2F(qm * p.z);
        g0 += e0; g1 += e1;
        f0 = fmaf(e0, p.y, f0);
        f1 = fmaf(e1, p.w, f1);
    }
    __syncthreads();
    Pf[t] = f0 + f1;
    Pg[t] = g0 + g1;
    __syncthreads();

    if (t < M_NODES) {
        const float4* pf4 = reinterpret_cast<const float4*>(Pf) + t * 4;
        const float4* pg4 = reinterpret_cast<const float4*>(Pg) + t * 4;
        float fs = 0.f, gs = 0.f;
#pragma unroll
        for (int i = 0; i < 4; ++i) {
            float4 a = pf4[i], b = pg4[i];
            fs += (a.x + a.y) + (a.z + a.w);
            gs += (b.x + b.y) + (b.z + b.w);
        }
        Rt[t] = fs / gs;
    }
    __syncthreads();

    const float u = (qv - qlo) * (1.0f / h);
    int i0 = (int)u;
    i0 = (i0 < 1) ? 1 : (i0 > M_NODES - 3 ? M_NODES - 3 : i0);
    const float tf = u - (float)i0;
    const float a  = Rt[i0 - 1];
    const float b  = Rt[i0];
    const float cc = Rt[i0 + 1];
    const float d  = Rt[i0 + 2];
    const float m0 = 0.5f * (cc - a);
    const float m1 = 0.5f * (d - b);
    const float dd = cc - b;
    const float r  = b + tf * (m0 + tf * ((3.f * dd - 2.f * m0 - m1)
                                          + tf * (m0 + m1 - 2.f * dd)));
    out[(size_t)n * DF + t] = r;
}

// ---------------------------------------------------------------------------
extern "C" void kernel_launch(void* const* d_in, const int* in_sizes, int n_in,
                              void* d_out, int out_size, void* d_ws, size_t ws_size,
                              hipStream_t stream) {
    const float* x  = (const float*)d_in[0];
    const float* Wq = (const float*)d_in[1];
    const float* bq = (const float*)d_in[2];
    const float* Wk = (const float*)d_in[3];
    const float* bk = (const float*)d_in[4];
    const float* Wv = (const float*)d_in[5];
    const float* bv = (const float*)d_in[6];

    char* ws = (char*)d_ws;
    float*     PTQ = (float*)(ws + PTQ_OFF);
    _Float16*  PTK = (_Float16*)(ws + PTK_OFF);
    _Float16*  PTV = (_Float16*)(ws + PTV_OFF);

    qkv_lds_kernel<<<dim3(9, 8, 9), 256, 0, stream>>>(
        x, Wq, Wk, Wv, PTQ, PTK, PTV);

    attn_interp_kernel<<<NR, DF, 0, stream>>>(
        PTQ, PTK, PTV, bq, bk, bv, (float*)d_out);
}